// Round 6
// baseline (313.335 us; speedup 1.0000x reference)
//
#include <hip/hip_runtime.h>
#include <hip/hip_bf16.h>
#include <stdint.h>

#define IN_F   4096
#define OUT_F  4096
#define BATCH  4096

typedef __bf16 bf16x8_t __attribute__((ext_vector_type(8)));
typedef float  f32x4_t  __attribute__((ext_vector_type(4)));
typedef float  f32x4v   __attribute__((ext_vector_type(4)));
typedef unsigned short u16x4v __attribute__((ext_vector_type(4)));

#define AS_GLOBAL(p) ((const __attribute__((address_space(1))) void*)(p))
#define AS_LDS(p)    ((__attribute__((address_space(3))) void*)(p))

__device__ __forceinline__ unsigned short f32_to_bf16_rne(float f) {
    union { float f; uint32_t u; } v; v.f = f;
    uint32_t u = v.u;
    u += 0x7FFFu + ((u >> 16) & 1u);
    return (unsigned short)(u >> 16);
}

// ---------------------------------------------------------------------------
// Pre-pass (round-0 proven verbatim): xb = bf16(x), wb = bf16(W * M).
// ---------------------------------------------------------------------------
__global__ __launch_bounds__(256)
void convert_kernel(const float* __restrict__ x,
                    const float* __restrict__ w,
                    const float* __restrict__ m,
                    unsigned short* __restrict__ xb,
                    unsigned short* __restrict__ wb) {
    const int64_t i0 = (int64_t)blockIdx.x * 512 + threadIdx.x;
#pragma unroll
    for (int u = 0; u < 2; ++u) {
        const int64_t i = i0 + u * 256;
        f32x4v xv = __builtin_nontemporal_load(&((const f32x4v*)x)[i]);
        f32x4v wv = __builtin_nontemporal_load(&((const f32x4v*)w)[i]);
        f32x4v mv = __builtin_nontemporal_load(&((const f32x4v*)m)[i]);
        u16x4v xo, wo;
        xo.x = f32_to_bf16_rne(xv.x);
        xo.y = f32_to_bf16_rne(xv.y);
        xo.z = f32_to_bf16_rne(xv.z);
        xo.w = f32_to_bf16_rne(xv.w);
        wo.x = f32_to_bf16_rne(wv.x * mv.x);
        wo.y = f32_to_bf16_rne(wv.y * mv.y);
        wo.z = f32_to_bf16_rne(wv.z * mv.z);
        wo.w = f32_to_bf16_rne(wv.w * mv.w);
        ((u16x4v*)xb)[i] = xo;
        ((u16x4v*)wb)[i] = wo;
    }
}

// ---------------------------------------------------------------------------
// 256x256 GEMM, BK=64, 512 thr (8 waves = 2M x 4N), LDS 128 KiB dbuf.
// Round-6: attack intra-tile LDS/MFMA serialization (measured 5060 cyc/tile
// = LDS 2560 + MFMA 2070 + barriers, i.e. the SUM not the MAX):
//   (1) ks-OUTER MFMA order per quadrant -- rounds 4/5 had ks innermost,
//       making every 2nd MFMA latency-stall on its accumulator (round-0's
//       928 TF kernel was ks-outer; regression introduced in the port).
//   (2) all 24 ds_read_b128 issued at tile top, FIFO-ordered by first use
//       (a0,b0,b1,a1) into DISTINCT register sets (96 frag VGPR; unified
//       budget 512/wave at 2 waves/SIMD -> no spill) so Q2/Q3's A-reads are
//       in flight during Q0/Q1 instead of bursting after Q1.
// Barrier/stage/vmcnt schedule = round-5 proven (2 barriers/tile, vmcnt(6)).
// Per-acc operand order unchanged (ks0 then ks1, Q0->Q3) -> bit-identical y.
// ---------------------------------------------------------------------------
#define BM 256
#define BN 256
#define BK 64
#define NT (IN_F / BK)   // 64

__global__ __launch_bounds__(512, 2)
void gemm_2bar_kernel(const unsigned short* __restrict__ A,   // [BATCH][IN_F]
                      const unsigned short* __restrict__ B,   // [OUT_F][IN_F]
                      const float* __restrict__ bias,
                      float* __restrict__ C) {
    __shared__ __align__(16) unsigned short sA[2][2][128 * 64];  // 64 KiB
    __shared__ __align__(16) unsigned short sB[2][2][128 * 64];  // 64 KiB

    const int t    = threadIdx.x;
    const int wv   = t >> 6;        // 0..7
    const int lane = t & 63;
    const int quad = lane >> 4;     // 0..3
    const int l16  = lane & 15;
    const int wr   = wv >> 2;       // 0..1 (M half)
    const int wc   = wv & 3;        // 0..3 (N quarter)
    const int bhalf = wc >> 1;      // which B half this wave reads
    const int brow0 = (wc & 1) * 64;

    // XCD-aware bijective swizzle over 256 blocks (256 % 8 == 0).
    const int bid = blockIdx.x;
    const int swz = (bid & 7) * 32 + (bid >> 3);
    const int bm  = (swz >> 4) * BM;
    const int bn  = (swz & 15) * BN;

    // Staging: thread t loads 16 B; row-in-half = rr*64 + (t>>3), source
    // k-chunk pre-swizzled by row&7 so LDS stays linear (rule 21).
    const int srow = t >> 3;                        // 0..63
    const int scol = 8 * ((t & 7) ^ (srow & 7));    // elements
    const unsigned short* gA = A + (int64_t)(bm + srow) * IN_F + scol;
    const unsigned short* gB = B + (int64_t)(bn + srow) * IN_F + scol;
    const int ldsoff = t * 16;

#define STAGE_A(TT, h)                                                        \
    do {                                                                      \
        _Pragma("unroll")                                                     \
        for (int rr = 0; rr < 2; ++rr)                                        \
            __builtin_amdgcn_global_load_lds(                                 \
                AS_GLOBAL(gA + (int64_t)((h) * 128 + rr * 64) * IN_F + (TT) * BK), \
                AS_LDS((char*)sA[(TT) & 1][h] + rr * 8192 + ldsoff), 16, 0, 0); \
    } while (0)
#define STAGE_B(TT, h)                                                        \
    do {                                                                      \
        _Pragma("unroll")                                                     \
        for (int rr = 0; rr < 2; ++rr)                                        \
            __builtin_amdgcn_global_load_lds(                                 \
                AS_GLOBAL(gB + (int64_t)((h) * 128 + rr * 64) * IN_F + (TT) * BK), \
                AS_LDS((char*)sB[(TT) & 1][h] + rr * 8192 + ldsoff), 16, 0, 0); \
    } while (0)

    f32x4_t acc[8][4];
#pragma unroll
    for (int mi = 0; mi < 8; ++mi)
#pragma unroll
        for (int ni = 0; ni < 4; ++ni)
            acc[mi][ni] = (f32x4_t){0.f, 0.f, 0.f, 0.f};

    // Prologue: tile 0 fully + 3 halves of tile 1 (steady-state invariant:
    // after the gate, outstanding = (T+1,B0),(T+1,B1),(T+1,A0) = 6 loads).
    STAGE_A(0, 0); STAGE_A(0, 1); STAGE_B(0, 0); STAGE_B(0, 1);
    STAGE_B(1, 0); STAGE_B(1, 1); STAGE_A(1, 0);
    asm volatile("s_waitcnt vmcnt(6)" ::: "memory");  // tile 0 landed
    __builtin_amdgcn_s_barrier();
    __builtin_amdgcn_sched_barrier(0);

    for (int T = 0; T < NT; ++T) {
        const unsigned short* myA = sA[T & 1][wr];
        const unsigned short* myB = sB[T & 1][bhalf];

        bf16x8_t a0[4][2], a1[4][2], b0[2][2], b1[2][2];

        // All 24 ds_read_b128 up front, FIFO order = first-use order:
        // a0 (Q0/Q1 A-rows 0-63), b0 (Q0/Q3), b1 (Q1/Q2), a1 (Q2/Q3 rows 64-127).
        // Compiler emits counted lgkmcnt before each quadrant's MFMAs.
#pragma unroll
        for (int j = 0; j < 4; ++j) {
            const int row = j * 16 + l16;
#pragma unroll
            for (int ks = 0; ks < 2; ++ks)
                a0[j][ks] = *(const bf16x8_t*)(myA + row * 64 +
                                ((ks * 4 + quad) ^ (row & 7)) * 8);
        }
#pragma unroll
        for (int j = 0; j < 2; ++j) {
            const int row = brow0 + j * 16 + l16;
#pragma unroll
            for (int ks = 0; ks < 2; ++ks)
                b0[j][ks] = *(const bf16x8_t*)(myB + row * 64 +
                                ((ks * 4 + quad) ^ (row & 7)) * 8);
        }
#pragma unroll
        for (int j = 0; j < 2; ++j) {
            const int row = brow0 + (j + 2) * 16 + l16;
#pragma unroll
            for (int ks = 0; ks < 2; ++ks)
                b1[j][ks] = *(const bf16x8_t*)(myB + row * 64 +
                                ((ks * 4 + quad) ^ (row & 7)) * 8);
        }
#pragma unroll
        for (int j = 0; j < 4; ++j) {
            const int row = (j + 4) * 16 + l16;
#pragma unroll
            for (int ks = 0; ks < 2; ++ks)
                a1[j][ks] = *(const bf16x8_t*)(myA + row * 64 +
                                ((ks * 4 + quad) ^ (row & 7)) * 8);
        }
        if (T + 1 < NT) STAGE_A(T + 1, 1);   // dbuf^1 A1: readers retired last tile

        __builtin_amdgcn_s_setprio(1);
        // ks-OUTER within each quadrant: 8 independent MFMAs between the
        // dependent ks0->ks1 accumulator reuses (per-acc order unchanged).
#pragma unroll
        for (int ks = 0; ks < 2; ++ks)       // Q0: acc[0-3][0-1]
#pragma unroll
            for (int mi = 0; mi < 4; ++mi)
#pragma unroll
                for (int ni = 0; ni < 2; ++ni)
                    acc[mi][ni] = __builtin_amdgcn_mfma_f32_16x16x32_bf16(
                        a0[mi][ks], b0[ni][ks], acc[mi][ni], 0, 0, 0);
#pragma unroll
        for (int ks = 0; ks < 2; ++ks)       // Q1: acc[0-3][2-3]
#pragma unroll
            for (int mi = 0; mi < 4; ++mi)
#pragma unroll
                for (int ni = 0; ni < 2; ++ni)
                    acc[mi][ni + 2] = __builtin_amdgcn_mfma_f32_16x16x32_bf16(
                        a0[mi][ks], b1[ni][ks], acc[mi][ni + 2], 0, 0, 0);
#pragma unroll
        for (int ks = 0; ks < 2; ++ks)       // Q2: acc[4-7][2-3]
#pragma unroll
            for (int mi = 0; mi < 4; ++mi)
#pragma unroll
                for (int ni = 0; ni < 2; ++ni)
                    acc[mi + 4][ni + 2] = __builtin_amdgcn_mfma_f32_16x16x32_bf16(
                        a1[mi][ks], b1[ni][ks], acc[mi + 4][ni + 2], 0, 0, 0);
#pragma unroll
        for (int ks = 0; ks < 2; ++ks)       // Q3: acc[4-7][0-1]
#pragma unroll
            for (int mi = 0; mi < 4; ++mi)
#pragma unroll
                for (int ni = 0; ni < 2; ++ni)
                    acc[mi + 4][ni] = __builtin_amdgcn_mfma_f32_16x16x32_bf16(
                        a1[mi][ks], b0[ni][ks], acc[mi + 4][ni], 0, 0, 0);
        __builtin_amdgcn_s_setprio(0);

        if (T + 1 < NT) {
            // barrier#1: every wave has consumed all its reads of dbuf T&1
            // -> safe to overwrite dbuf regions below.
            __builtin_amdgcn_s_barrier();
            __builtin_amdgcn_sched_barrier(0);
            if (T + 2 < NT) { STAGE_B(T + 2, 0); STAGE_B(T + 2, 1); STAGE_A(T + 2, 0); }
            if (T < NT - 2)
                asm volatile("s_waitcnt vmcnt(6)" ::: "memory");   // tile T+1 landed
            else
                asm volatile("s_waitcnt vmcnt(0)" ::: "memory");   // drain tail
            // barrier#2: publish tile T+1 to all waves.
            __builtin_amdgcn_s_barrier();
            __builtin_amdgcn_sched_barrier(0);
        }
    }

    // Epilogue: C/D layout col = lane&15 (n), row = quad*4 + reg (m).
    float bv[4];
#pragma unroll
    for (int ni = 0; ni < 4; ++ni)
        bv[ni] = bias[bn + wc * 64 + ni * 16 + l16];

#pragma unroll
    for (int mi = 0; mi < 8; ++mi) {
        const int row0 = bm + wr * 128 + mi * 16 + quad * 4;
#pragma unroll
        for (int ni = 0; ni < 4; ++ni) {
            const int col = bn + wc * 64 + ni * 16 + l16;
#pragma unroll
            for (int reg = 0; reg < 4; ++reg)
                C[(int64_t)(row0 + reg) * OUT_F + col] = acc[mi][ni][reg] + bv[ni];
        }
    }
#undef STAGE_A
#undef STAGE_B
}

// ---------------------------------------------------------------------------
// Fallback (workspace too small): plain fp32 tiled GEMM.
// ---------------------------------------------------------------------------
__global__ void fallback_gemm_kernel(const float* __restrict__ x,
                                     const float* __restrict__ w,
                                     const float* __restrict__ bias,
                                     const float* __restrict__ m,
                                     float* __restrict__ y) {
    __shared__ float sx[16][17];
    __shared__ float sw[16][17];
    const int tx = threadIdx.x, ty = threadIdx.y;
    const int row = blockIdx.y * 16 + ty;
    const int col = blockIdx.x * 16 + tx;
    float acc = 0.f;
    for (int k0 = 0; k0 < IN_F; k0 += 16) {
        sx[ty][tx] = x[(int64_t)row * IN_F + k0 + tx];
        const int64_t widx = (int64_t)(blockIdx.x * 16 + ty) * IN_F + k0 + tx;
        sw[ty][tx] = w[widx] * m[widx];
        __syncthreads();
#pragma unroll
        for (int kk = 0; kk < 16; ++kk)
            acc += sx[ty][kk] * sw[tx][kk];
        __syncthreads();
    }
    y[(int64_t)row * OUT_F + col] = acc + bias[col];
}

// ---------------------------------------------------------------------------
extern "C" void kernel_launch(void* const* d_in, const int* in_sizes, int n_in,
                              void* d_out, int out_size, void* d_ws, size_t ws_size,
                              hipStream_t stream) {
    const float* x    = (const float*)d_in[0];
    const float* w    = (const float*)d_in[1];
    const float* bias = (const float*)d_in[2];
    const float* m    = (const float*)d_in[3];
    float* y = (float*)d_out;

    const size_t need = (size_t)2 * (size_t)OUT_F * (size_t)IN_F * sizeof(unsigned short);

    if (ws_size >= need) {
        unsigned short* xb = (unsigned short*)d_ws;
        unsigned short* wb = xb + (size_t)BATCH * IN_F;

        convert_kernel<<<8192, 256, 0, stream>>>(x, w, m, xb, wb);

        gemm_2bar_kernel<<<256, 512, 0, stream>>>(xb, wb, bias, y);
    } else {
        dim3 grid(OUT_F / 16, BATCH / 16);
        dim3 block(16, 16);
        fallback_gemm_kernel<<<grid, block, 0, stream>>>(x, w, bias, m, y);
    }
}